// Round 9
// baseline (520.484 us; speedup 1.0000x reference)
//
#include <hip/hip_runtime.h>
#include <hip/hip_bf16.h>
#include <hip/hip_fp16.h>
#include <math.h>

// ---------------------------------------------------------------------------
// GAT 2-layer forward.
// R9: aggregate gather restructured to quarter-wave-per-edge (C=64: 16
//     lanes/edge, ushort8/lane -> 4 edges per wave-instruction; C=32: 8
//     lanes/edge -> 8 edges/instr). One float4 LDS record per edge slot.
//     edge_w single-pass (register-held logits) for deg<=64. wcvt merged.
// Pipeline: CSR build (bucketed) -> gemm_attn_mfma (fp16 MFMA) -> edge_w ->
//     aggregate (pure weighted gather).
// ---------------------------------------------------------------------------

#define BINBITS 9                 // nodes per bucket = 512
#define NBUCK 256                 // covers N < 131072
#define CHUNK 4096                // edges per WG in binA
#define SPANCAP 12288             // LDS staging capacity in binB (ints)

typedef _Float16 half8 __attribute__((ext_vector_type(8)));
typedef float f32x4 __attribute__((ext_vector_type(4)));

// ------------------------- CSR build -------------------------

__global__ void init_kernel(int* __restrict__ bcnt) {
    bcnt[threadIdx.x] = 0;
}

__global__ void bucket_hist_kernel(const int* __restrict__ dst, int* __restrict__ bcnt, int E) {
    __shared__ int h[NBUCK];
    int t = threadIdx.x;
    h[t] = 0;
    __syncthreads();
    for (int i = blockIdx.x * blockDim.x + t; i < E; i += gridDim.x * blockDim.x)
        atomicAdd(&h[dst[i] >> BINBITS], 1);
    __syncthreads();
    if (h[t]) atomicAdd(&bcnt[t], h[t]);
}

__global__ void bucket_scan_kernel(const int* __restrict__ bcnt, int* __restrict__ bbase,
                                   int* __restrict__ bfill) {
    __shared__ int sd[NBUCK];
    int t = threadIdx.x;
    int v = bcnt[t];
    sd[t] = v;
    __syncthreads();
    for (int o = 1; o < NBUCK; o <<= 1) {
        int x = (t >= o) ? sd[t - o] : 0;
        __syncthreads();
        sd[t] += x;
        __syncthreads();
    }
    int exc = sd[t] - v;
    bbase[t] = exc;
    bfill[t] = exc;
    if (t == NBUCK - 1) bbase[NBUCK] = sd[t];  // = E
}

__launch_bounds__(256)
__global__ void binA_kernel(const int* __restrict__ esrc, const int* __restrict__ edst,
                            int* __restrict__ bfill, unsigned* __restrict__ binned, int E) {
    __shared__ unsigned stage[CHUNK];
    __shared__ int hcnt[NBUCK], hexc[NBUCK], gb[NBUCK], hfill[NBUCK];
    const int tid = threadIdx.x;
    const int c0 = blockIdx.x * CHUNK;
    const int n = min(CHUNK, E - c0);

    hcnt[tid] = 0;
    hfill[tid] = 0;
    __syncthreads();
    for (int i = tid; i < n; i += 256) atomicAdd(&hcnt[edst[c0 + i] >> BINBITS], 1);
    __syncthreads();
    int myc = hcnt[tid];
    hexc[tid] = myc;
    __syncthreads();
    for (int o = 1; o < NBUCK; o <<= 1) {       // inclusive scan
        int x = (tid >= o) ? hexc[tid - o] : 0;
        __syncthreads();
        hexc[tid] += x;
        __syncthreads();
    }
    hexc[tid] -= myc;                           // exclusive
    gb[tid] = myc ? atomicAdd(&bfill[tid], myc) : 0;
    __syncthreads();

    for (int i = tid; i < n; i += 256) {
        int d = edst[c0 + i], s = esrc[c0 + i];
        int b = d >> BINBITS;
        int p = hexc[b] + atomicAdd(&hfill[b], 1);
        stage[p] = ((unsigned)(d & ((1 << BINBITS) - 1)) << 17) | (unsigned)s;
    }
    __syncthreads();

    const int wid = tid >> 6, lane = tid & 63;
    for (int b = wid * 64; b < wid * 64 + 64; ++b) {
        int cnt = hcnt[b], sb = hexc[b], g = gb[b];
        for (int l = lane; l < cnt; l += 64) binned[g + l] = stage[sb + l];
    }
}

// binB: per-bucket local rowptr derivation + LDS-staged fine scatter.
__launch_bounds__(256)
__global__ void binB_kernel(const unsigned* __restrict__ binned, const int* __restrict__ bbase,
                            int* __restrict__ rowptr, int* __restrict__ csr, int N) {
    __shared__ int cnt[512];           // degree count, then reused as fill
    __shared__ int chunk[256];
    __shared__ int excl[513];
    __shared__ int stag[SPANCAP];
    const int tid = threadIdx.x;
    const int b = blockIdx.x;
    const int node0 = b << BINBITS;
    if (node0 >= N) return;
    const int nn = min(512, N - node0);

    cnt[tid] = (tid < nn) ? 1 : 0;            // self-loop
    cnt[tid + 256] = (tid + 256 < nn) ? 1 : 0;
    __syncthreads();
    const int e0 = bbase[b], e1 = bbase[b + 1];
    for (int i = e0 + tid; i < e1; i += 256)
        atomicAdd(&cnt[binned[i] >> 17], 1);
    __syncthreads();

    int c0v = cnt[2 * tid], c1v = cnt[2 * tid + 1];
    chunk[tid] = c0v + c1v;
    __syncthreads();
    int v = chunk[tid];
    for (int o = 1; o < 256; o <<= 1) {
        int x = (tid >= o) ? chunk[tid - o] : 0;
        __syncthreads();
        chunk[tid] += x;
        __syncthreads();
    }
    int cpre = chunk[tid] - v;                // exclusive chunk prefix
    excl[2 * tid] = cpre;
    excl[2 * tid + 1] = cpre + c0v;
    if (tid == 255) excl[512] = cpre + c0v + c1v;
    __syncthreads();

    const int rbase = e0 + node0;             // == rowptr[node0]
    for (int i = tid; i < nn; i += 256) rowptr[node0 + i] = rbase + excl[i];
    if (node0 + nn >= N && tid == 0) rowptr[N] = rbase + excl[512];

    cnt[tid] = 0;
    cnt[tid + 256] = 0;
    __syncthreads();
    const int span = excl[512];

    if (span <= SPANCAP) {
        for (int i = e0 + tid; i < e1; i += 256) {
            unsigned e = binned[i];
            int dloc = e >> 17, src = e & 0x1FFFF;
            int p = excl[dloc] + atomicAdd(&cnt[dloc], 1);
            stag[p] = src;
        }
        for (int i = tid; i < nn; i += 256) {
            int p = excl[i] + atomicAdd(&cnt[i], 1);
            stag[p] = node0 + i;
        }
        __syncthreads();
        for (int i = tid; i < span; i += 256) csr[rbase + i] = stag[i];
    } else {
        for (int i = e0 + tid; i < e1; i += 256) {
            unsigned e = binned[i];
            int dloc = e >> 17, src = e & 0x1FFFF;
            csr[rbase + excl[dloc] + atomicAdd(&cnt[dloc], 1)] = src;
        }
        for (int i = tid; i < nn; i += 256)
            csr[rbase + excl[i] + atomicAdd(&cnt[i], 1)] = node0 + i;
    }
}

// ------------------- W -> fp16 transposed (both layers, one dispatch) -----

__global__ void wcvt_kernel(const float* __restrict__ W1, _Float16* __restrict__ Wt1,
                            const float* __restrict__ W2, _Float16* __restrict__ Wt2) {
    int i = blockIdx.x * 256 + threadIdx.x;
    if (i < 128 * 128) {
        int n = i >> 7, k = i & 127;
        Wt1[i] = (_Float16)W1[k * 128 + n];
    }
    int j = i - 128 * 128;
    if (j >= 0 && j < 64 * 64) {
        int n = j >> 6, k = j & 63;
        Wt2[j] = (_Float16)W2[k * 64 + n];
    }
}

// ------------------- MFMA GEMM (fp16 in, fp32 acc) + attn epilogue -------
// 256 threads = 4 waves; block tile BM=128 rows x FOUT cols, whole K in LDS.
// Layouts (verified): A[m=lane&15][k=quad*8+j]  B[k=quad*8+j][n=lane&15]
//   C/D: col=lane&15, row=quad*4+reg

template <int FIN, int FOUT, typename XT>
__launch_bounds__(256)
__global__ void gemm_attn_mfma(const XT* __restrict__ X, const _Float16* __restrict__ Wt,
                               const float* __restrict__ atts, const float* __restrict__ attd,
                               __half* __restrict__ Hh, float* __restrict__ a_s,
                               float* __restrict__ a_d, int N) {
    constexpr int BM = 128;
    constexpr int C = FOUT / 2;
    constexpr int NT = FOUT / 16;     // n-tiles per wave (8 / 4)
    constexpr int KS = FIN / 32;      // k-steps (4 / 2)
    constexpr int HT = C / 16;        // n-tiles per head
    __shared__ _Float16 sA[BM * FIN];
    __shared__ _Float16 sB[FOUT * FIN];

    const int tid = threadIdx.x;
    const int wv = tid >> 6, ln = tid & 63;
    const int lm = ln & 15, quad = ln >> 4;
    const int row0 = blockIdx.x * BM;

    // ---- stage A (rows, k contiguous) ----
    if (sizeof(XT) == 4) {
        for (int idx = tid; idx < BM * FIN / 4; idx += 256) {
            int r = idx / (FIN / 4), c4 = idx % (FIN / 4);
            int gr = row0 + r;
            float4 v = make_float4(0.f, 0.f, 0.f, 0.f);
            if (gr < N) v = *(const float4*)&((const float*)X)[(size_t)gr * FIN + c4 * 4];
            _Float16 h4[4] = {(_Float16)v.x, (_Float16)v.y, (_Float16)v.z, (_Float16)v.w};
            *(float2*)&sA[r * FIN + c4 * 4] = *(float2*)h4;
        }
    } else {
        for (int idx = tid; idx < BM * FIN / 8; idx += 256) {
            int r = idx / (FIN / 8), c8 = idx % (FIN / 8);
            int gr = row0 + r;
            int4 v = make_int4(0, 0, 0, 0);
            if (gr < N) v = *(const int4*)&((const __half*)X)[(size_t)gr * FIN + c8 * 8];
            *(int4*)&sA[r * FIN + c8 * 8] = v;
        }
    }
    // ---- stage B (Wt contiguous copy) ----
    for (int idx = tid; idx < FOUT * FIN / 8; idx += 256)
        *(int4*)&sB[idx * 8] = *(const int4*)&Wt[idx * 8];
    __syncthreads();

    // ---- MFMA K-loop ----
    f32x4 acc[2][NT];
#pragma unroll
    for (int mt = 0; mt < 2; ++mt)
#pragma unroll
        for (int nt = 0; nt < NT; ++nt) acc[mt][nt] = f32x4{0.f, 0.f, 0.f, 0.f};

    const int r0 = wv * 32 + lm;
#pragma unroll
    for (int ks = 0; ks < KS; ++ks) {
        int k0 = ks * 32 + quad * 8;
        half8 a0 = *(const half8*)&sA[r0 * FIN + k0];
        half8 a1 = *(const half8*)&sA[(r0 + 16) * FIN + k0];
#pragma unroll
        for (int nt = 0; nt < NT; ++nt) {
            half8 b = *(const half8*)&sB[(nt * 16 + lm) * FIN + k0];
            acc[0][nt] = __builtin_amdgcn_mfma_f32_16x16x32_f16(a0, b, acc[0][nt], 0, 0, 0);
            acc[1][nt] = __builtin_amdgcn_mfma_f32_16x16x32_f16(a1, b, acc[1][nt], 0, 0, 0);
        }
    }

    // ---- attn scalars from fp32 acc ----
    float psum[2][4][2], pdum[2][4][2];  // [mt][reg][head]
#pragma unroll
    for (int mt = 0; mt < 2; ++mt)
#pragma unroll
        for (int r = 0; r < 4; ++r) {
            psum[mt][r][0] = psum[mt][r][1] = 0.f;
            pdum[mt][r][0] = pdum[mt][r][1] = 0.f;
        }
#pragma unroll
    for (int nt = 0; nt < NT; ++nt) {
        float av = atts[nt * 16 + lm];
        float dv = attd[nt * 16 + lm];
        int hh = nt / HT;
#pragma unroll
        for (int mt = 0; mt < 2; ++mt)
#pragma unroll
            for (int r = 0; r < 4; ++r) {
                psum[mt][r][hh] = fmaf(acc[mt][nt][r], av, psum[mt][r][hh]);
                pdum[mt][r][hh] = fmaf(acc[mt][nt][r], dv, pdum[mt][r][hh]);
            }
    }
#pragma unroll
    for (int o = 1; o < 16; o <<= 1) {
#pragma unroll
        for (int mt = 0; mt < 2; ++mt)
#pragma unroll
            for (int r = 0; r < 4; ++r) {
                psum[mt][r][0] += __shfl_xor(psum[mt][r][0], o);
                psum[mt][r][1] += __shfl_xor(psum[mt][r][1], o);
                pdum[mt][r][0] += __shfl_xor(pdum[mt][r][0], o);
                pdum[mt][r][1] += __shfl_xor(pdum[mt][r][1], o);
            }
    }
    if (lm == 0) {
#pragma unroll
        for (int mt = 0; mt < 2; ++mt)
#pragma unroll
            for (int r = 0; r < 4; ++r) {
                int gr = row0 + wv * 32 + mt * 16 + quad * 4 + r;
                if (gr < N) {
                    *(float2*)&a_s[gr * 2] = make_float2(psum[mt][r][0], psum[mt][r][1]);
                    *(float2*)&a_d[gr * 2] = make_float2(pdum[mt][r][0], pdum[mt][r][1]);
                }
            }
    }

    // ---- h -> fp16 via LDS transpose (reuse sA), coalesced store ----
    __syncthreads();
    _Float16* sH = sA;  // BM*FOUT <= BM*FIN
#pragma unroll
    for (int mt = 0; mt < 2; ++mt)
#pragma unroll
        for (int nt = 0; nt < NT; ++nt)
#pragma unroll
            for (int r = 0; r < 4; ++r)
                sH[(wv * 32 + mt * 16 + quad * 4 + r) * FOUT + nt * 16 + lm] =
                    (_Float16)acc[mt][nt][r];
    __syncthreads();
    for (int idx = tid; idx < BM * FOUT / 8; idx += 256) {
        int r = idx / (FOUT / 8), c8 = idx % (FOUT / 8);
        int gr = row0 + r;
        if (gr < N)
            *(int4*)&Hh[(size_t)gr * FOUT + c8 * 8] = *(const int4*)&sH[r * FOUT + c8 * 8];
    }
}

// --------------------- edge weights (normalized) ---------------------
// Single pass for deg <= 64 (logits register-held through the denom
// reduction -> no w[] RMW); strided two-pass fallback for rare long rows.

__device__ __forceinline__ float lrelu02(float x) { return x > 0.f ? x : 0.2f * x; }

__launch_bounds__(256)
__global__ void edge_w_kernel(const float* __restrict__ a_s, const float* __restrict__ a_d,
                              const int* __restrict__ rowptr, const int* __restrict__ csr,
                              float2* __restrict__ w, int N) {
    const int wid = threadIdx.x >> 6, lane = threadIdx.x & 63;
    int n = blockIdx.x * 4 + wid;
    if (n >= N) return;
    int start = rowptr[n], end = rowptr[n + 1];
    int deg = end - start;
    float2 adn = ((const float2*)a_d)[n];

    if (deg <= 64) {
        float e0 = 0.f, e1 = 0.f;
        int j = start + lane;
        if (lane < deg) {
            int s = csr[j];
            float2 asv = ((const float2*)a_s)[s];
            e0 = __expf(lrelu02(asv.x + adn.x));
            e1 = __expf(lrelu02(asv.y + adn.y));
        }
        float d0 = e0, d1 = e1;
#pragma unroll
        for (int o = 32; o > 0; o >>= 1) {
            d0 += __shfl_xor(d0, o);
            d1 += __shfl_xor(d1, o);
        }
        float i0 = 0.5f / d0, i1 = 0.5f / d1;   // 0.5 = head mean
        if (lane < deg) w[j] = make_float2(e0 * i0, e1 * i1);
    } else {
        float d0 = 0.f, d1 = 0.f;
        for (int j = start + lane; j < end; j += 64) {
            int s = csr[j];
            float2 asv = ((const float2*)a_s)[s];
            float e0 = __expf(lrelu02(asv.x + adn.x));
            float e1 = __expf(lrelu02(asv.y + adn.y));
            d0 += e0;
            d1 += e1;
            w[j] = make_float2(e0, e1);
        }
#pragma unroll
        for (int o = 32; o > 0; o >>= 1) {
            d0 += __shfl_xor(d0, o);
            d1 += __shfl_xor(d1, o);
        }
        float i0 = 0.5f / d0, i1 = 0.5f / d1;
        for (int j = start + lane; j < end; j += 64) {
            float2 f = w[j];
            w[j] = make_float2(f.x * i0, f.y * i1);
        }
    }
}

// ------------------------- gather aggregation (R9) -------------------------
// One wave per node. Weight phase: lane j writes slot j's float4
// {w0, w1, srcbits, 0} (w=0 pad for j >= deg). Gather phase: LPE lanes per
// edge (C=64: LPE=16, 4 edges/instr; C=32: LPE=8, 8 edges/instr), each lane
// loads ushort8 (int4) = 8 channels of its edge's h row. Channels: global
// ch = sub*8..sub*8+7 spanning both heads; head = sub >> (log2(LPE)-1).
// 4 batches in flight. Merges: shfl over edge subsets, then head fold
// (0.5/denom pre-folded into w), then LPE/2 lanes write 8 ch each.

template <int C, bool ELU, typename OT>
__launch_bounds__(256)
__global__ void aggregate_kernel(const __half* __restrict__ Hh, const float2* __restrict__ w,
                                 const int* __restrict__ rowptr, const int* __restrict__ csr,
                                 const float* __restrict__ bias, OT* __restrict__ out, int N) {
    constexpr int LPE = (C == 64) ? 16 : 8;   // lanes per edge
    constexpr int NG = 64 / LPE;              // edges per batch
    constexpr int RI = C / 4;                 // int4 per h row (2C halves)
    __shared__ float4 swR[4][64];             // [wave][slot] = (w0, w1, src, 0)
    const int wid = threadIdx.x >> 6;
    const int lane = threadIdx.x & 63;
    const int sub = lane & (LPE - 1);
    const int qid = lane / LPE;               // edge-within-batch
    const int isH1 = (sub >= LPE / 2);        // this lane's head
    int n = blockIdx.x * 4 + wid;
    if (n >= N) return;
    int start = rowptr[n], end = rowptr[n + 1];
    const int4* HI = (const int4*)Hh;

    float av[8];
#pragma unroll
    for (int j = 0; j < 8; ++j) av[j] = 0.f;

    for (int cs = start; cs < end; cs += 64) {
        int j = cs + lane;
        float2 wv = make_float2(0.f, 0.f);
        int s = 0;
        if (j < end) {
            s = csr[j];
            wv = w[j];
        }
        swR[wid][lane] = make_float4(wv.x, wv.y, __int_as_float(s), 0.f);
        int cnt = min(64, end - cs);
        int nbatch = (cnt + NG - 1) / NG;
        for (int b = 0; b < nbatch; b += 4) {
            float4 r[4];
#pragma unroll
            for (int u = 0; u < 4; ++u)
                r[u] = swR[wid][(b + u) * NG + qid];   // slot <= 63; pad w=0
            int4 hv[4];
#pragma unroll
            for (int u = 0; u < 4; ++u)
                hv[u] = HI[(size_t)__float_as_int(r[u].z) * RI + sub];
#pragma unroll
            for (int u = 0; u < 4; ++u) {
                float ww = isH1 ? r[u].y : r[u].x;
                const __half2* h2 = (const __half2*)&hv[u];
#pragma unroll
                for (int p = 0; p < 4; ++p) {
                    float2 f = __half22float2(h2[p]);
                    av[2 * p] = fmaf(ww, f.x, av[2 * p]);
                    av[2 * p + 1] = fmaf(ww, f.y, av[2 * p + 1]);
                }
            }
        }
    }

    // merge edge subsets (groups of LPE lanes)
#pragma unroll
    for (int o = LPE; o < 64; o <<= 1)
#pragma unroll
        for (int j = 0; j < 8; ++j) av[j] += __shfl_xor(av[j], o);
    // head fold (0.5/denom already in w): head0 ch at sub < LPE/2
#pragma unroll
    for (int j = 0; j < 8; ++j) av[j] += __shfl_xor(av[j], LPE / 2);

    if (lane < LPE / 2) {
        float4 b0 = *(const float4*)(bias + sub * 8);
        float4 b1 = *(const float4*)(bias + sub * 8 + 4);
        float o0[8];
        o0[0] = av[0] + b0.x; o0[1] = av[1] + b0.y;
        o0[2] = av[2] + b0.z; o0[3] = av[3] + b0.w;
        o0[4] = av[4] + b1.x; o0[5] = av[5] + b1.y;
        o0[6] = av[6] + b1.z; o0[7] = av[7] + b1.w;
        if (ELU) {
#pragma unroll
            for (int j = 0; j < 8; ++j) o0[j] = o0[j] > 0.f ? o0[j] : expm1f(o0[j]);
        }
        if (sizeof(OT) == 2) {
            union { int4 v; __half2 h2[4]; } u;
#pragma unroll
            for (int p = 0; p < 4; ++p) u.h2[p] = __floats2half2_rn(o0[2 * p], o0[2 * p + 1]);
            *(int4*)((__half*)out + (size_t)n * C + sub * 8) = u.v;
        } else {
            *(float4*)((float*)out + (size_t)n * C + sub * 8) =
                make_float4(o0[0], o0[1], o0[2], o0[3]);
            *(float4*)((float*)out + (size_t)n * C + sub * 8 + 4) =
                make_float4(o0[4], o0[5], o0[6], o0[7]);
        }
    }
}

// ------------------------- launch -------------------------

extern "C" void kernel_launch(void* const* d_in, const int* in_sizes, int n_in,
                              void* d_out, int out_size, void* d_ws, size_t ws_size,
                              hipStream_t stream) {
    const float* x    = (const float*)d_in[0];
    const int*   eidx = (const int*)d_in[1];
    const float* W1   = (const float*)d_in[2];
    const float* as1w = (const float*)d_in[3];
    const float* ad1w = (const float*)d_in[4];
    const float* b1   = (const float*)d_in[5];
    const float* W2   = (const float*)d_in[6];
    const float* as2w = (const float*)d_in[7];
    const float* ad2w = (const float*)d_in[8];
    const float* b2   = (const float*)d_in[9];
    float* out = (float*)d_out;

    const int N = in_sizes[0] / 128;  // Fin = 128
    const int E = in_sizes[1] / 2;
    const int NBK = (N + (1 << BINBITS) - 1) >> BINBITS;

    char* base = (char*)d_ws;
    size_t off = 0;
    auto alloc = [&](size_t bytes) {
        size_t cur = off;
        off += (bytes + 255) & ~(size_t)255;
        return (void*)(base + cur);
    };

    int* rowptr   = (int*)alloc((size_t)(N + 1) * 4);
    int* csr      = (int*)alloc((size_t)(E + N) * 4);
    int* bcnt     = (int*)alloc((size_t)NBUCK * 4);
    int* bbase    = (int*)alloc((size_t)(NBUCK + 1) * 4);
    int* bfill    = (int*)alloc((size_t)NBUCK * 4);
    unsigned* binned = (unsigned*)alloc((size_t)E * 4);
    __half* h1    = (__half*)alloc((size_t)N * 128 * 2);  // fp16, reused as h2
    __half* x2h   = (__half*)alloc((size_t)N * 64 * 2);   // fp16 layer-2 input
    float* a_s    = (float*)alloc((size_t)N * 2 * 4);
    float* a_d    = (float*)alloc((size_t)N * 2 * 4);
    float2* wEdge = (float2*)alloc((size_t)(E + N) * 8);
    _Float16* Wt1 = (_Float16*)alloc((size_t)128 * 128 * 2);
    _Float16* Wt2 = (_Float16*)alloc((size_t)64 * 64 * 2);

    const int* esrc = eidx;
    const int* edst = eidx + E;

    // --- CSR build (shared by both layers) ---
    init_kernel<<<1, NBUCK, 0, stream>>>(bcnt);
    bucket_hist_kernel<<<256, 256, 0, stream>>>(edst, bcnt, E);
    bucket_scan_kernel<<<1, NBUCK, 0, stream>>>(bcnt, bbase, bfill);
    binA_kernel<<<(E + CHUNK - 1) / CHUNK, 256, 0, stream>>>(esrc, edst, bfill, binned, E);
    binB_kernel<<<NBK, 256, 0, stream>>>(binned, bbase, rowptr, csr, N);

    // --- weight conversion (fp16, transposed; both layers) ---
    wcvt_kernel<<<(128 * 128 + 64 * 64 + 255) / 256, 256, 0, stream>>>(W1, Wt1, W2, Wt2);

    // --- Layer 1 (Fin=128 -> H=2, C=64) ---
    gemm_attn_mfma<128, 128, float>
        <<<(N + 127) / 128, 256, 0, stream>>>(x, Wt1, as1w, ad1w, h1, a_s, a_d, N);
    edge_w_kernel<<<(N + 3) / 4, 256, 0, stream>>>(a_s, a_d, rowptr, csr, wEdge, N);
    aggregate_kernel<64, true, __half>
        <<<(N + 3) / 4, 256, 0, stream>>>(h1, wEdge, rowptr, csr, b1, x2h, N);

    // --- Layer 2 (Fin=64 -> H=2, C=32) ---
    gemm_attn_mfma<64, 64, __half>
        <<<(N + 127) / 128, 256, 0, stream>>>(x2h, Wt2, as2w, ad2w, h1, a_s, a_d, N);
    edge_w_kernel<<<(N + 3) / 4, 256, 0, stream>>>(a_s, a_d, rowptr, csr, wEdge, N);
    aggregate_kernel<32, false, float>
        <<<(N + 3) / 4, 256, 0, stream>>>(h1, wEdge, rowptr, csr, b2, out, N);
}

// Round 10
// 370.772 us; speedup vs baseline: 1.4038x; 1.4038x over previous
//
#include <hip/hip_runtime.h>
#include <hip/hip_bf16.h>
#include <hip/hip_fp16.h>
#include <math.h>

// ---------------------------------------------------------------------------
// GAT 2-layer forward.
// R10: R9's quarter-wave gather kept, but LDS records reverted to the proven
//      conflict-free per-head float2 format (ds_read_b64, consecutive-8B
//      addresses; R9's float4/b128 layout caused 41.7M bank-conflict cycles).
// Pipeline: CSR build (bucketed) -> gemm_attn_mfma (fp16 MFMA) -> edge_w
//      (single-pass, normalized) -> aggregate (pure weighted gather).
// ---------------------------------------------------------------------------

#define BINBITS 9                 // nodes per bucket = 512
#define NBUCK 256                 // covers N < 131072
#define CHUNK 4096                // edges per WG in binA
#define SPANCAP 12288             // LDS staging capacity in binB (ints)

typedef _Float16 half8 __attribute__((ext_vector_type(8)));
typedef float f32x4 __attribute__((ext_vector_type(4)));

// ------------------------- CSR build -------------------------

__global__ void init_kernel(int* __restrict__ bcnt) {
    bcnt[threadIdx.x] = 0;
}

__global__ void bucket_hist_kernel(const int* __restrict__ dst, int* __restrict__ bcnt, int E) {
    __shared__ int h[NBUCK];
    int t = threadIdx.x;
    h[t] = 0;
    __syncthreads();
    for (int i = blockIdx.x * blockDim.x + t; i < E; i += gridDim.x * blockDim.x)
        atomicAdd(&h[dst[i] >> BINBITS], 1);
    __syncthreads();
    if (h[t]) atomicAdd(&bcnt[t], h[t]);
}

__global__ void bucket_scan_kernel(const int* __restrict__ bcnt, int* __restrict__ bbase,
                                   int* __restrict__ bfill) {
    __shared__ int sd[NBUCK];
    int t = threadIdx.x;
    int v = bcnt[t];
    sd[t] = v;
    __syncthreads();
    for (int o = 1; o < NBUCK; o <<= 1) {
        int x = (t >= o) ? sd[t - o] : 0;
        __syncthreads();
        sd[t] += x;
        __syncthreads();
    }
    int exc = sd[t] - v;
    bbase[t] = exc;
    bfill[t] = exc;
    if (t == NBUCK - 1) bbase[NBUCK] = sd[t];  // = E
}

__launch_bounds__(256)
__global__ void binA_kernel(const int* __restrict__ esrc, const int* __restrict__ edst,
                            int* __restrict__ bfill, unsigned* __restrict__ binned, int E) {
    __shared__ unsigned stage[CHUNK];
    __shared__ int hcnt[NBUCK], hexc[NBUCK], gb[NBUCK], hfill[NBUCK];
    const int tid = threadIdx.x;
    const int c0 = blockIdx.x * CHUNK;
    const int n = min(CHUNK, E - c0);

    hcnt[tid] = 0;
    hfill[tid] = 0;
    __syncthreads();
    for (int i = tid; i < n; i += 256) atomicAdd(&hcnt[edst[c0 + i] >> BINBITS], 1);
    __syncthreads();
    int myc = hcnt[tid];
    hexc[tid] = myc;
    __syncthreads();
    for (int o = 1; o < NBUCK; o <<= 1) {       // inclusive scan
        int x = (tid >= o) ? hexc[tid - o] : 0;
        __syncthreads();
        hexc[tid] += x;
        __syncthreads();
    }
    hexc[tid] -= myc;                           // exclusive
    gb[tid] = myc ? atomicAdd(&bfill[tid], myc) : 0;
    __syncthreads();

    for (int i = tid; i < n; i += 256) {
        int d = edst[c0 + i], s = esrc[c0 + i];
        int b = d >> BINBITS;
        int p = hexc[b] + atomicAdd(&hfill[b], 1);
        stage[p] = ((unsigned)(d & ((1 << BINBITS) - 1)) << 17) | (unsigned)s;
    }
    __syncthreads();

    const int wid = tid >> 6, lane = tid & 63;
    for (int b = wid * 64; b < wid * 64 + 64; ++b) {
        int cnt = hcnt[b], sb = hexc[b], g = gb[b];
        for (int l = lane; l < cnt; l += 64) binned[g + l] = stage[sb + l];
    }
}

// binB: per-bucket local rowptr derivation + LDS-staged fine scatter.
__launch_bounds__(256)
__global__ void binB_kernel(const unsigned* __restrict__ binned, const int* __restrict__ bbase,
                            int* __restrict__ rowptr, int* __restrict__ csr, int N) {
    __shared__ int cnt[512];           // degree count, then reused as fill
    __shared__ int chunk[256];
    __shared__ int excl[513];
    __shared__ int stag[SPANCAP];
    const int tid = threadIdx.x;
    const int b = blockIdx.x;
    const int node0 = b << BINBITS;
    if (node0 >= N) return;
    const int nn = min(512, N - node0);

    cnt[tid] = (tid < nn) ? 1 : 0;            // self-loop
    cnt[tid + 256] = (tid + 256 < nn) ? 1 : 0;
    __syncthreads();
    const int e0 = bbase[b], e1 = bbase[b + 1];
    for (int i = e0 + tid; i < e1; i += 256)
        atomicAdd(&cnt[binned[i] >> 17], 1);
    __syncthreads();

    int c0v = cnt[2 * tid], c1v = cnt[2 * tid + 1];
    chunk[tid] = c0v + c1v;
    __syncthreads();
    int v = chunk[tid];
    for (int o = 1; o < 256; o <<= 1) {
        int x = (tid >= o) ? chunk[tid - o] : 0;
        __syncthreads();
        chunk[tid] += x;
        __syncthreads();
    }
    int cpre = chunk[tid] - v;                // exclusive chunk prefix
    excl[2 * tid] = cpre;
    excl[2 * tid + 1] = cpre + c0v;
    if (tid == 255) excl[512] = cpre + c0v + c1v;
    __syncthreads();

    const int rbase = e0 + node0;             // == rowptr[node0]
    for (int i = tid; i < nn; i += 256) rowptr[node0 + i] = rbase + excl[i];
    if (node0 + nn >= N && tid == 0) rowptr[N] = rbase + excl[512];

    cnt[tid] = 0;
    cnt[tid + 256] = 0;
    __syncthreads();
    const int span = excl[512];

    if (span <= SPANCAP) {
        for (int i = e0 + tid; i < e1; i += 256) {
            unsigned e = binned[i];
            int dloc = e >> 17, src = e & 0x1FFFF;
            int p = excl[dloc] + atomicAdd(&cnt[dloc], 1);
            stag[p] = src;
        }
        for (int i = tid; i < nn; i += 256) {
            int p = excl[i] + atomicAdd(&cnt[i], 1);
            stag[p] = node0 + i;
        }
        __syncthreads();
        for (int i = tid; i < span; i += 256) csr[rbase + i] = stag[i];
    } else {
        for (int i = e0 + tid; i < e1; i += 256) {
            unsigned e = binned[i];
            int dloc = e >> 17, src = e & 0x1FFFF;
            csr[rbase + excl[dloc] + atomicAdd(&cnt[dloc], 1)] = src;
        }
        for (int i = tid; i < nn; i += 256)
            csr[rbase + excl[i] + atomicAdd(&cnt[i], 1)] = node0 + i;
    }
}

// ------------------- W -> fp16 transposed (both layers, one dispatch) -----

__global__ void wcvt_kernel(const float* __restrict__ W1, _Float16* __restrict__ Wt1,
                            const float* __restrict__ W2, _Float16* __restrict__ Wt2) {
    int i = blockIdx.x * 256 + threadIdx.x;
    if (i < 128 * 128) {
        int n = i >> 7, k = i & 127;
        Wt1[i] = (_Float16)W1[k * 128 + n];
    }
    int j = i - 128 * 128;
    if (j >= 0 && j < 64 * 64) {
        int n = j >> 6, k = j & 63;
        Wt2[j] = (_Float16)W2[k * 64 + n];
    }
}

// ------------------- MFMA GEMM (fp16 in, fp32 acc) + attn epilogue -------
// 256 threads = 4 waves; block tile BM=128 rows x FOUT cols, whole K in LDS.
// Layouts (verified): A[m=lane&15][k=quad*8+j]  B[k=quad*8+j][n=lane&15]
//   C/D: col=lane&15, row=quad*4+reg

template <int FIN, int FOUT, typename XT>
__launch_bounds__(256)
__global__ void gemm_attn_mfma(const XT* __restrict__ X, const _Float16* __restrict__ Wt,
                               const float* __restrict__ atts, const float* __restrict__ attd,
                               __half* __restrict__ Hh, float* __restrict__ a_s,
                               float* __restrict__ a_d, int N) {
    constexpr int BM = 128;
    constexpr int C = FOUT / 2;
    constexpr int NT = FOUT / 16;     // n-tiles per wave (8 / 4)
    constexpr int KS = FIN / 32;      // k-steps (4 / 2)
    constexpr int HT = C / 16;        // n-tiles per head
    __shared__ _Float16 sA[BM * FIN];
    __shared__ _Float16 sB[FOUT * FIN];

    const int tid = threadIdx.x;
    const int wv = tid >> 6, ln = tid & 63;
    const int lm = ln & 15, quad = ln >> 4;
    const int row0 = blockIdx.x * BM;

    // ---- stage A (rows, k contiguous) ----
    if (sizeof(XT) == 4) {
        for (int idx = tid; idx < BM * FIN / 4; idx += 256) {
            int r = idx / (FIN / 4), c4 = idx % (FIN / 4);
            int gr = row0 + r;
            float4 v = make_float4(0.f, 0.f, 0.f, 0.f);
            if (gr < N) v = *(const float4*)&((const float*)X)[(size_t)gr * FIN + c4 * 4];
            _Float16 h4[4] = {(_Float16)v.x, (_Float16)v.y, (_Float16)v.z, (_Float16)v.w};
            *(float2*)&sA[r * FIN + c4 * 4] = *(float2*)h4;
        }
    } else {
        for (int idx = tid; idx < BM * FIN / 8; idx += 256) {
            int r = idx / (FIN / 8), c8 = idx % (FIN / 8);
            int gr = row0 + r;
            int4 v = make_int4(0, 0, 0, 0);
            if (gr < N) v = *(const int4*)&((const __half*)X)[(size_t)gr * FIN + c8 * 8];
            *(int4*)&sA[r * FIN + c8 * 8] = v;
        }
    }
    // ---- stage B (Wt contiguous copy) ----
    for (int idx = tid; idx < FOUT * FIN / 8; idx += 256)
        *(int4*)&sB[idx * 8] = *(const int4*)&Wt[idx * 8];
    __syncthreads();

    // ---- MFMA K-loop ----
    f32x4 acc[2][NT];
#pragma unroll
    for (int mt = 0; mt < 2; ++mt)
#pragma unroll
        for (int nt = 0; nt < NT; ++nt) acc[mt][nt] = f32x4{0.f, 0.f, 0.f, 0.f};

    const int r0 = wv * 32 + lm;
#pragma unroll
    for (int ks = 0; ks < KS; ++ks) {
        int k0 = ks * 32 + quad * 8;
        half8 a0 = *(const half8*)&sA[r0 * FIN + k0];
        half8 a1 = *(const half8*)&sA[(r0 + 16) * FIN + k0];
#pragma unroll
        for (int nt = 0; nt < NT; ++nt) {
            half8 b = *(const half8*)&sB[(nt * 16 + lm) * FIN + k0];
            acc[0][nt] = __builtin_amdgcn_mfma_f32_16x16x32_f16(a0, b, acc[0][nt], 0, 0, 0);
            acc[1][nt] = __builtin_amdgcn_mfma_f32_16x16x32_f16(a1, b, acc[1][nt], 0, 0, 0);
        }
    }

    // ---- attn scalars from fp32 acc ----
    float psum[2][4][2], pdum[2][4][2];  // [mt][reg][head]
#pragma unroll
    for (int mt = 0; mt < 2; ++mt)
#pragma unroll
        for (int r = 0; r < 4; ++r) {
            psum[mt][r][0] = psum[mt][r][1] = 0.f;
            pdum[mt][r][0] = pdum[mt][r][1] = 0.f;
        }
#pragma unroll
    for (int nt = 0; nt < NT; ++nt) {
        float av = atts[nt * 16 + lm];
        float dv = attd[nt * 16 + lm];
        int hh = nt / HT;
#pragma unroll
        for (int mt = 0; mt < 2; ++mt)
#pragma unroll
            for (int r = 0; r < 4; ++r) {
                psum[mt][r][hh] = fmaf(acc[mt][nt][r], av, psum[mt][r][hh]);
                pdum[mt][r][hh] = fmaf(acc[mt][nt][r], dv, pdum[mt][r][hh]);
            }
    }
#pragma unroll
    for (int o = 1; o < 16; o <<= 1) {
#pragma unroll
        for (int mt = 0; mt < 2; ++mt)
#pragma unroll
            for (int r = 0; r < 4; ++r) {
                psum[mt][r][0] += __shfl_xor(psum[mt][r][0], o);
                psum[mt][r][1] += __shfl_xor(psum[mt][r][1], o);
                pdum[mt][r][0] += __shfl_xor(pdum[mt][r][0], o);
                pdum[mt][r][1] += __shfl_xor(pdum[mt][r][1], o);
            }
    }
    if (lm == 0) {
#pragma unroll
        for (int mt = 0; mt < 2; ++mt)
#pragma unroll
            for (int r = 0; r < 4; ++r) {
                int gr = row0 + wv * 32 + mt * 16 + quad * 4 + r;
                if (gr < N) {
                    *(float2*)&a_s[gr * 2] = make_float2(psum[mt][r][0], psum[mt][r][1]);
                    *(float2*)&a_d[gr * 2] = make_float2(pdum[mt][r][0], pdum[mt][r][1]);
                }
            }
    }

    // ---- h -> fp16 via LDS transpose (reuse sA), coalesced store ----
    __syncthreads();
    _Float16* sH = sA;  // BM*FOUT <= BM*FIN
#pragma unroll
    for (int mt = 0; mt < 2; ++mt)
#pragma unroll
        for (int nt = 0; nt < NT; ++nt)
#pragma unroll
            for (int r = 0; r < 4; ++r)
                sH[(wv * 32 + mt * 16 + quad * 4 + r) * FOUT + nt * 16 + lm] =
                    (_Float16)acc[mt][nt][r];
    __syncthreads();
    for (int idx = tid; idx < BM * FOUT / 8; idx += 256) {
        int r = idx / (FOUT / 8), c8 = idx % (FOUT / 8);
        int gr = row0 + r;
        if (gr < N)
            *(int4*)&Hh[(size_t)gr * FOUT + c8 * 8] = *(const int4*)&sH[r * FOUT + c8 * 8];
    }
}

// --------------------- edge weights (normalized) ---------------------
// Single pass for deg <= 64 (logits register-held through the denom
// reduction -> no w[] RMW); strided two-pass fallback for rare long rows.

__device__ __forceinline__ float lrelu02(float x) { return x > 0.f ? x : 0.2f * x; }

__launch_bounds__(256)
__global__ void edge_w_kernel(const float* __restrict__ a_s, const float* __restrict__ a_d,
                              const int* __restrict__ rowptr, const int* __restrict__ csr,
                              float2* __restrict__ w, int N) {
    const int wid = threadIdx.x >> 6, lane = threadIdx.x & 63;
    int n = blockIdx.x * 4 + wid;
    if (n >= N) return;
    int start = rowptr[n], end = rowptr[n + 1];
    int deg = end - start;
    float2 adn = ((const float2*)a_d)[n];

    if (deg <= 64) {
        float e0 = 0.f, e1 = 0.f;
        int j = start + lane;
        if (lane < deg) {
            int s = csr[j];
            float2 asv = ((const float2*)a_s)[s];
            e0 = __expf(lrelu02(asv.x + adn.x));
            e1 = __expf(lrelu02(asv.y + adn.y));
        }
        float d0 = e0, d1 = e1;
#pragma unroll
        for (int o = 32; o > 0; o >>= 1) {
            d0 += __shfl_xor(d0, o);
            d1 += __shfl_xor(d1, o);
        }
        float i0 = 0.5f / d0, i1 = 0.5f / d1;   // 0.5 = head mean
        if (lane < deg) w[j] = make_float2(e0 * i0, e1 * i1);
    } else {
        float d0 = 0.f, d1 = 0.f;
        for (int j = start + lane; j < end; j += 64) {
            int s = csr[j];
            float2 asv = ((const float2*)a_s)[s];
            float e0 = __expf(lrelu02(asv.x + adn.x));
            float e1 = __expf(lrelu02(asv.y + adn.y));
            d0 += e0;
            d1 += e1;
            w[j] = make_float2(e0, e1);
        }
#pragma unroll
        for (int o = 32; o > 0; o >>= 1) {
            d0 += __shfl_xor(d0, o);
            d1 += __shfl_xor(d1, o);
        }
        float i0 = 0.5f / d0, i1 = 0.5f / d1;
        for (int j = start + lane; j < end; j += 64) {
            float2 f = w[j];
            w[j] = make_float2(f.x * i0, f.y * i1);
        }
    }
}

// ------------------------- gather aggregation (R10) ------------------------
// One wave per node. Weight phase: lane j writes slot j's per-head float2
// records {w_h, srcbits} (w=0 pad for j >= deg). Gather: LPE lanes per edge
// (C=64: LPE=16, 4 edges/instr; C=32: LPE=8, 8 edges/instr), lane loads
// int4 = 8 channels (ch sub*8..+7 spanning both heads; head = upper half of
// sub range). Records read as ds_read_b64 at consecutive-8B addresses --
// conflict-free (R7-verified pattern). 4 batches in flight. Merges: shfl
// over edge subsets, head fold (0.5/denom pre-folded), LPE/2 lanes write.

template <int C, bool ELU, typename OT>
__launch_bounds__(256)
__global__ void aggregate_kernel(const __half* __restrict__ Hh, const float2* __restrict__ w,
                                 const int* __restrict__ rowptr, const int* __restrict__ csr,
                                 const float* __restrict__ bias, OT* __restrict__ out, int N) {
    constexpr int LPE = (C == 64) ? 16 : 8;   // lanes per edge
    constexpr int NG = 64 / LPE;              // edges per batch
    constexpr int RI = C / 4;                 // int4 per h row (2C halves)
    __shared__ float2 swH[4][64][2];          // [wave][slot][head] = (w, src)
    const int wid = threadIdx.x >> 6;
    const int lane = threadIdx.x & 63;
    const int sub = lane & (LPE - 1);
    const int qid = lane / LPE;               // edge-within-batch
    const int myH = (sub >= LPE / 2);         // this lane's head
    int n = blockIdx.x * 4 + wid;
    if (n >= N) return;
    int start = rowptr[n], end = rowptr[n + 1];
    const int4* HI = (const int4*)Hh;

    float av[8];
#pragma unroll
    for (int j = 0; j < 8; ++j) av[j] = 0.f;

    for (int cs = start; cs < end; cs += 64) {
        int j = cs + lane;
        float2 wv = make_float2(0.f, 0.f);
        int s = 0;
        if (j < end) {
            s = csr[j];
            wv = w[j];
        }
        float fs = __int_as_float(s);
        swH[wid][lane][0] = make_float2(wv.x, fs);
        swH[wid][lane][1] = make_float2(wv.y, fs);
        int cnt = min(64, end - cs);
        int nbatch = (cnt + NG - 1) / NG;     // <= 64/NG -> slot <= 63 always
        for (int b = 0; b < nbatch; b += 4) {
            float2 e[4];
#pragma unroll
            for (int u = 0; u < 4; ++u)
                e[u] = swH[wid][(b + u) * NG + qid][myH];   // pad slots: w=0
            int4 hv[4];
#pragma unroll
            for (int u = 0; u < 4; ++u)
                hv[u] = HI[(size_t)__float_as_int(e[u].y) * RI + sub];
#pragma unroll
            for (int u = 0; u < 4; ++u) {
                float ww = e[u].x;
                const __half2* h2 = (const __half2*)&hv[u];
#pragma unroll
                for (int p = 0; p < 4; ++p) {
                    float2 f = __half22float2(h2[p]);
                    av[2 * p] = fmaf(ww, f.x, av[2 * p]);
                    av[2 * p + 1] = fmaf(ww, f.y, av[2 * p + 1]);
                }
            }
        }
    }

    // merge edge subsets (groups of LPE lanes)
#pragma unroll
    for (int o = LPE; o < 64; o <<= 1)
#pragma unroll
        for (int j = 0; j < 8; ++j) av[j] += __shfl_xor(av[j], o);
    // head fold (0.5/denom already in w): ch c (head0) + ch c+C (head1)
#pragma unroll
    for (int j = 0; j < 8; ++j) av[j] += __shfl_xor(av[j], LPE / 2);

    if (lane < LPE / 2) {
        float4 b0 = *(const float4*)(bias + sub * 8);
        float4 b1 = *(const float4*)(bias + sub * 8 + 4);
        float o0[8];
        o0[0] = av[0] + b0.x; o0[1] = av[1] + b0.y;
        o0[2] = av[2] + b0.z; o0[3] = av[3] + b0.w;
        o0[4] = av[4] + b1.x; o0[5] = av[5] + b1.y;
        o0[6] = av[6] + b1.z; o0[7] = av[7] + b1.w;
        if (ELU) {
#pragma unroll
            for (int j = 0; j < 8; ++j) o0[j] = o0[j] > 0.f ? o0[j] : expm1f(o0[j]);
        }
        if (sizeof(OT) == 2) {
            union { int4 v; __half2 h2[4]; } u;
#pragma unroll
            for (int p = 0; p < 4; ++p) u.h2[p] = __floats2half2_rn(o0[2 * p], o0[2 * p + 1]);
            *(int4*)((__half*)out + (size_t)n * C + sub * 8) = u.v;
        } else {
            *(float4*)((float*)out + (size_t)n * C + sub * 8) =
                make_float4(o0[0], o0[1], o0[2], o0[3]);
            *(float4*)((float*)out + (size_t)n * C + sub * 8 + 4) =
                make_float4(o0[4], o0[5], o0[6], o0[7]);
        }
    }
}

// ------------------------- launch -------------------------

extern "C" void kernel_launch(void* const* d_in, const int* in_sizes, int n_in,
                              void* d_out, int out_size, void* d_ws, size_t ws_size,
                              hipStream_t stream) {
    const float* x    = (const float*)d_in[0];
    const int*   eidx = (const int*)d_in[1];
    const float* W1   = (const float*)d_in[2];
    const float* as1w = (const float*)d_in[3];
    const float* ad1w = (const float*)d_in[4];
    const float* b1   = (const float*)d_in[5];
    const float* W2   = (const float*)d_in[6];
    const float* as2w = (const float*)d_in[7];
    const float* ad2w = (const float*)d_in[8];
    const float* b2   = (const float*)d_in[9];
    float* out = (float*)d_out;

    const int N = in_sizes[0] / 128;  // Fin = 128
    const int E = in_sizes[1] / 2;
    const int NBK = (N + (1 << BINBITS) - 1) >> BINBITS;

    char* base = (char*)d_ws;
    size_t off = 0;
    auto alloc = [&](size_t bytes) {
        size_t cur = off;
        off += (bytes + 255) & ~(size_t)255;
        return (void*)(base + cur);
    };

    int* rowptr   = (int*)alloc((size_t)(N + 1) * 4);
    int* csr      = (int*)alloc((size_t)(E + N) * 4);
    int* bcnt     = (int*)alloc((size_t)NBUCK * 4);
    int* bbase    = (int*)alloc((size_t)(NBUCK + 1) * 4);
    int* bfill    = (int*)alloc((size_t)NBUCK * 4);
    unsigned* binned = (unsigned*)alloc((size_t)E * 4);
    __half* h1    = (__half*)alloc((size_t)N * 128 * 2);  // fp16, reused as h2
    __half* x2h   = (__half*)alloc((size_t)N * 64 * 2);   // fp16 layer-2 input
    float* a_s    = (float*)alloc((size_t)N * 2 * 4);
    float* a_d    = (float*)alloc((size_t)N * 2 * 4);
    float2* wEdge = (float2*)alloc((size_t)(E + N) * 8);
    _Float16* Wt1 = (_Float16*)alloc((size_t)128 * 128 * 2);
    _Float16* Wt2 = (_Float16*)alloc((size_t)64 * 64 * 2);

    const int* esrc = eidx;
    const int* edst = eidx + E;

    // --- CSR build (shared by both layers) ---
    init_kernel<<<1, NBUCK, 0, stream>>>(bcnt);
    bucket_hist_kernel<<<256, 256, 0, stream>>>(edst, bcnt, E);
    bucket_scan_kernel<<<1, NBUCK, 0, stream>>>(bcnt, bbase, bfill);
    binA_kernel<<<(E + CHUNK - 1) / CHUNK, 256, 0, stream>>>(esrc, edst, bfill, binned, E);
    binB_kernel<<<NBK, 256, 0, stream>>>(binned, bbase, rowptr, csr, N);

    // --- weight conversion (fp16, transposed; both layers) ---
    wcvt_kernel<<<(128 * 128 + 64 * 64 + 255) / 256, 256, 0, stream>>>(W1, Wt1, W2, Wt2);

    // --- Layer 1 (Fin=128 -> H=2, C=64) ---
    gemm_attn_mfma<128, 128, float>
        <<<(N + 127) / 128, 256, 0, stream>>>(x, Wt1, as1w, ad1w, h1, a_s, a_d, N);
    edge_w_kernel<<<(N + 3) / 4, 256, 0, stream>>>(a_s, a_d, rowptr, csr, wEdge, N);
    aggregate_kernel<64, true, __half>
        <<<(N + 3) / 4, 256, 0, stream>>>(h1, wEdge, rowptr, csr, b1, x2h, N);

    // --- Layer 2 (Fin=64 -> H=2, C=32) ---
    gemm_attn_mfma<64, 64, __half>
        <<<(N + 127) / 128, 256, 0, stream>>>(x2h, Wt2, as2w, ad2w, h1, a_s, a_d, N);
    edge_w_kernel<<<(N + 3) / 4, 256, 0, stream>>>(a_s, a_d, rowptr, csr, wEdge, N);
    aggregate_kernel<32, false, float>
        <<<(N + 3) / 4, 256, 0, stream>>>(h1, wEdge, rowptr, csr, b2, out, N);
}